// Round 1
// baseline (285.887 us; speedup 1.0000x reference)
//
#include <hip/hip_runtime.h>
#include <stdint.h>

#define NB 32
#define NL 8192
#define ND 1024
#define NTOPK 100
#define CAND_CAP 3072

// ---------------------------------------------------------------------------
// Kernel 1: fused triple projection.
// One wave (64 lanes) per (b,l) row. Lane reads 4 float4s of x (coalesced),
// accumulates 3 dot products, butterfly-reduce, lane 0 writes results.
// ---------------------------------------------------------------------------
__global__ __launch_bounds__(256) void proj_kernel(
    const float* __restrict__ x, const float* __restrict__ sal,
    const float* __restrict__ Wc, const float* __restrict__ bc,
    const float* __restrict__ Ww, const float* __restrict__ bw,
    const float* __restrict__ Wo, const float* __restrict__ bo,
    float* __restrict__ center, float* __restrict__ window_,
    float* __restrict__ offset)
{
    const int wid  = (int)((blockIdx.x * (unsigned)blockDim.x + threadIdx.x) >> 6);
    const int lane = (int)(threadIdx.x & 63u);
    if (wid >= NB * NL) return;

    const float4* x4  = (const float4*)x + (size_t)wid * (ND / 4);
    const float4* wc4 = (const float4*)Wc;
    const float4* ww4 = (const float4*)Ww;
    const float4* wo4 = (const float4*)Wo;

    float dc = 0.f, dw = 0.f, dz = 0.f;
#pragma unroll
    for (int j = 0; j < 4; ++j) {
        const int k = lane + 64 * j;
        const float4 xv = x4[k];
        const float4 wc = wc4[k];
        const float4 ww = ww4[k];
        const float4 wo = wo4[k];
        dc += xv.x * wc.x + xv.y * wc.y + xv.z * wc.z + xv.w * wc.w;
        dw += xv.x * ww.x + xv.y * ww.y + xv.z * ww.z + xv.w * ww.w;
        dz += xv.x * wo.x + xv.y * wo.y + xv.z * wo.z + xv.w * wo.w;
    }
#pragma unroll
    for (int s = 32; s > 0; s >>= 1) {
        dc += __shfl_xor(dc, s, 64);
        dw += __shfl_xor(dw, s, 64);
        dz += __shfl_xor(dz, s, 64);
    }
    if (lane == 0) {
        const float m = (sal[wid] >= 0.f) ? 1.f : 0.f;
        const float zc = dc + bc[0];
        center[wid]  = m / (1.f + expf(-zc));   // sigmoid * mask
        window_[wid] = dw + bw[0];
        offset[wid]  = dz + bo[0];
    }
}

// ---------------------------------------------------------------------------
// Kernel 2: per-batch-row NMS + exact top-100 + boundary computation.
// One block (1024 threads) per batch row.
// Key encoding: (float_bits << 32) | (0xFFFFFFFF - idx). For cp >= 0 the float
// bit pattern is monotonic, so uint64 '>' == (value desc, index asc) — exactly
// jax.lax.top_k tie-breaking.
// ---------------------------------------------------------------------------
__device__ __forceinline__ void emit_one(
    int b, int rank, int idx, float val,
    const float* __restrict__ window_, const float* __restrict__ offset,
    float* __restrict__ out)
{
    const float off = offset[b * NL + idx];
    float win = window_[b * NL + idx];
    win = fmaxf(win, 0.f);
    float c = (float)idx + off;
    c = fminf(fmaxf(c, 0.f), (float)(NL - 1));
    float s = fminf(fmaxf(c - 0.5f * win, 0.f), (float)(NL - 1)) * 2.0f;
    float e = fminf(fmaxf(c + 0.5f * win, 0.f), (float)(NL - 1)) * 2.0f + 2.0f;
    float* o = out + ((size_t)b * NTOPK + rank) * 3;
    o[0] = s;
    o[1] = e;
    o[2] = val;
}

__global__ __launch_bounds__(1024) void topk_kernel(
    const float* __restrict__ center, const float* __restrict__ window_,
    const float* __restrict__ offset, float* __restrict__ out)
{
    __shared__ float c[NL];                       // 32 KB
    __shared__ unsigned long long cand[CAND_CAP]; // 24 KB
    __shared__ int cnt;

    const int b   = blockIdx.x;
    const int tid = (int)threadIdx.x;

    if (tid == 0) cnt = 0;

    // stage center row into LDS (coalesced)
#pragma unroll
    for (int k = 0; k < NL / 1024; ++k)
        c[tid + k * 1024] = center[b * NL + tid + k * 1024];
    __syncthreads();

    // NMS: keep i iff c[i] > 0 and c[i] == max over window [i-2, i+2]
#pragma unroll
    for (int k = 0; k < NL / 1024; ++k) {
        const int i = tid + k * 1024;
        const float v = c[i];
        if (v > 0.f) {
            float lm = v;
            if (i >= 2)      lm = fmaxf(lm, c[i - 2]);
            if (i >= 1)      lm = fmaxf(lm, c[i - 1]);
            if (i + 1 < NL)  lm = fmaxf(lm, c[i + 1]);
            if (i + 2 < NL)  lm = fmaxf(lm, c[i + 2]);
            if (v == lm) {
                const int pos = atomicAdd(&cnt, 1);
                if (pos < CAND_CAP) {
                    const unsigned long long key =
                        ((unsigned long long)__float_as_uint(v) << 32) |
                        (unsigned long long)(0xFFFFFFFFu - (unsigned)i);
                    cand[pos] = key;
                }
            }
        }
    }
    __syncthreads();

    const int C = (cnt < CAND_CAP) ? cnt : CAND_CAP;

    // exact rank by counting (keys are unique -> ranks are a permutation)
    for (int i = tid; i < C; i += 1024) {
        const unsigned long long ki = cand[i];
        int r = 0;
        for (int j = 0; j < C; ++j) r += (cand[j] > ki) ? 1 : 0;
        if (r < NTOPK) {
            const int idx = (int)(0xFFFFFFFFu - (unsigned)(ki & 0xFFFFFFFFull));
            const float val = __uint_as_float((unsigned)(ki >> 32));
            emit_one(b, r, idx, val, window_, offset, out);
        }
    }

    // fallback: fewer than 100 positive candidates -> fill with cp==0 entries
    // in ascending index order (top_k tie-break), score 0.
    if (C < NTOPK) {
        __syncthreads();
        if (tid == 0) {
            int r = C;
            for (int i = 0; i < NL && r < NTOPK; ++i) {
                const float v = c[i];
                bool keep = false;
                if (v > 0.f) {
                    float lm = v;
                    if (i >= 2)     lm = fmaxf(lm, c[i - 2]);
                    if (i >= 1)     lm = fmaxf(lm, c[i - 1]);
                    if (i + 1 < NL) lm = fmaxf(lm, c[i + 1]);
                    if (i + 2 < NL) lm = fmaxf(lm, c[i + 2]);
                    keep = (v == lm);
                }
                if (!keep) {  // cp == 0 at this position
                    emit_one(b, r, i, 0.f, window_, offset, out);
                    ++r;
                }
            }
        }
    }
}

// ---------------------------------------------------------------------------
extern "C" void kernel_launch(void* const* d_in, const int* in_sizes, int n_in,
                              void* d_out, int out_size, void* d_ws, size_t ws_size,
                              hipStream_t stream)
{
    const float* x   = (const float*)d_in[0];
    const float* sal = (const float*)d_in[1];
    const float* Wc  = (const float*)d_in[2];
    const float* bc  = (const float*)d_in[3];
    const float* Ww  = (const float*)d_in[4];
    const float* bw  = (const float*)d_in[5];
    const float* Wo  = (const float*)d_in[6];
    const float* bo  = (const float*)d_in[7];
    float* out = (float*)d_out;

    float* ws      = (float*)d_ws;
    float* center  = ws;                 // [NB*NL]
    float* window_ = ws + NB * NL;       // [NB*NL]
    float* offset  = ws + 2 * NB * NL;   // [NB*NL]

    // Kernel 1: one wave per row, 4 waves per block
    const int rows = NB * NL;
    const int blocks = rows / 4;  // 65536
    proj_kernel<<<blocks, 256, 0, stream>>>(x, sal, Wc, bc, Ww, bw, Wo, bo,
                                            center, window_, offset);

    // Kernel 2: one block per batch row
    topk_kernel<<<NB, 1024, 0, stream>>>(center, window_, offset, out);
}

// Round 2
// 278.990 us; speedup vs baseline: 1.0247x; 1.0247x over previous
//
#include <hip/hip_runtime.h>
#include <stdint.h>

#define NB 32
#define NL 8192
#define ND 1024
#define NTOPK 100
#define CAND_CAP 3072

#define NBLOCKS 1024          // 1024 blocks x 256 thr = 4096 waves
#define ROWS_PER_WAVE ((NB * NL) / (NBLOCKS * 4))   // = 8

// ---------------------------------------------------------------------------
// Kernel 1: fused triple projection, weight-in-register version.
// Each wave owns ROWS_PER_WAVE consecutive rows. The 12 weight float4s
// (Wc,Ww,Wo interleaved across lanes) are loaded ONCE into registers, then
// each row costs only 4 x-float4 loads (the unique HBM traffic).
// ---------------------------------------------------------------------------
__global__ __launch_bounds__(256) void proj_kernel(
    const float* __restrict__ x, const float* __restrict__ sal,
    const float* __restrict__ Wc, const float* __restrict__ bc,
    const float* __restrict__ Ww, const float* __restrict__ bw,
    const float* __restrict__ Wo, const float* __restrict__ bo,
    float* __restrict__ center, float* __restrict__ window_,
    float* __restrict__ offset)
{
    const int wid  = (int)((blockIdx.x * (unsigned)blockDim.x + threadIdx.x) >> 6);
    const int lane = (int)(threadIdx.x & 63u);

    const float4* wc4 = (const float4*)Wc;
    const float4* ww4 = (const float4*)Ww;
    const float4* wo4 = (const float4*)Wo;

    // hoist weights into registers (48 VGPRs)
    float4 wc[4], ww[4], wo[4];
#pragma unroll
    for (int j = 0; j < 4; ++j) {
        const int k = lane + 64 * j;
        wc[j] = wc4[k];
        ww[j] = ww4[k];
        wo[j] = wo4[k];
    }
    const float bcs = bc[0], bws = bw[0], bos = bo[0];

    const int row0 = wid * ROWS_PER_WAVE;

#pragma unroll 2
    for (int r = 0; r < ROWS_PER_WAVE; ++r) {
        const int row = row0 + r;
        const float4* x4 = (const float4*)x + (size_t)row * (ND / 4);

        float4 xv[4];
#pragma unroll
        for (int j = 0; j < 4; ++j) xv[j] = x4[lane + 64 * j];

        float dc = 0.f, dw = 0.f, dz = 0.f;
#pragma unroll
        for (int j = 0; j < 4; ++j) {
            dc += xv[j].x * wc[j].x + xv[j].y * wc[j].y + xv[j].z * wc[j].z + xv[j].w * wc[j].w;
            dw += xv[j].x * ww[j].x + xv[j].y * ww[j].y + xv[j].z * ww[j].z + xv[j].w * ww[j].w;
            dz += xv[j].x * wo[j].x + xv[j].y * wo[j].y + xv[j].z * wo[j].z + xv[j].w * wo[j].w;
        }
#pragma unroll
        for (int s = 32; s > 0; s >>= 1) {
            dc += __shfl_xor(dc, s, 64);
            dw += __shfl_xor(dw, s, 64);
            dz += __shfl_xor(dz, s, 64);
        }
        if (lane == 0) {
            const float m = (sal[row] >= 0.f) ? 1.f : 0.f;
            const float zc = dc + bcs;
            center[row]  = m / (1.f + expf(-zc));   // sigmoid * mask
            window_[row] = dw + bws;
            offset[row]  = dz + bos;
        }
    }
}

// ---------------------------------------------------------------------------
// Kernel 2: per-batch-row NMS + exact top-100 + boundary computation.
// One block (1024 threads) per batch row.
// Key encoding: (float_bits << 32) | (0xFFFFFFFF - idx). For cp >= 0 the float
// bit pattern is monotonic, so uint64 '>' == (value desc, index asc) — exactly
// jax.lax.top_k tie-breaking.
// ---------------------------------------------------------------------------
__device__ __forceinline__ void emit_one(
    int b, int rank, int idx, float val,
    const float* __restrict__ window_, const float* __restrict__ offset,
    float* __restrict__ out)
{
    const float off = offset[b * NL + idx];
    float win = window_[b * NL + idx];
    win = fmaxf(win, 0.f);
    float c = (float)idx + off;
    c = fminf(fmaxf(c, 0.f), (float)(NL - 1));
    float s = fminf(fmaxf(c - 0.5f * win, 0.f), (float)(NL - 1)) * 2.0f;
    float e = fminf(fmaxf(c + 0.5f * win, 0.f), (float)(NL - 1)) * 2.0f + 2.0f;
    float* o = out + ((size_t)b * NTOPK + rank) * 3;
    o[0] = s;
    o[1] = e;
    o[2] = val;
}

__global__ __launch_bounds__(1024) void topk_kernel(
    const float* __restrict__ center, const float* __restrict__ window_,
    const float* __restrict__ offset, float* __restrict__ out)
{
    __shared__ float c[NL];                       // 32 KB
    __shared__ unsigned long long cand[CAND_CAP]; // 24 KB
    __shared__ int cnt;

    const int b   = blockIdx.x;
    const int tid = (int)threadIdx.x;

    if (tid == 0) cnt = 0;

    // stage center row into LDS (coalesced)
#pragma unroll
    for (int k = 0; k < NL / 1024; ++k)
        c[tid + k * 1024] = center[b * NL + tid + k * 1024];
    __syncthreads();

    // NMS: keep i iff c[i] > 0 and c[i] == max over window [i-2, i+2]
#pragma unroll
    for (int k = 0; k < NL / 1024; ++k) {
        const int i = tid + k * 1024;
        const float v = c[i];
        if (v > 0.f) {
            float lm = v;
            if (i >= 2)      lm = fmaxf(lm, c[i - 2]);
            if (i >= 1)      lm = fmaxf(lm, c[i - 1]);
            if (i + 1 < NL)  lm = fmaxf(lm, c[i + 1]);
            if (i + 2 < NL)  lm = fmaxf(lm, c[i + 2]);
            if (v == lm) {
                const int pos = atomicAdd(&cnt, 1);
                if (pos < CAND_CAP) {
                    const unsigned long long key =
                        ((unsigned long long)__float_as_uint(v) << 32) |
                        (unsigned long long)(0xFFFFFFFFu - (unsigned)i);
                    cand[pos] = key;
                }
            }
        }
    }
    __syncthreads();

    const int C = (cnt < CAND_CAP) ? cnt : CAND_CAP;

    // exact rank by counting (keys are unique -> ranks are a permutation)
    for (int i = tid; i < C; i += 1024) {
        const unsigned long long ki = cand[i];
        int r = 0;
        for (int j = 0; j < C; ++j) r += (cand[j] > ki) ? 1 : 0;
        if (r < NTOPK) {
            const int idx = (int)(0xFFFFFFFFu - (unsigned)(ki & 0xFFFFFFFFull));
            const float val = __uint_as_float((unsigned)(ki >> 32));
            emit_one(b, r, idx, val, window_, offset, out);
        }
    }

    // fallback: fewer than 100 positive candidates -> fill with cp==0 entries
    // in ascending index order (top_k tie-break), score 0.
    if (C < NTOPK) {
        __syncthreads();
        if (tid == 0) {
            int r = C;
            for (int i = 0; i < NL && r < NTOPK; ++i) {
                const float v = c[i];
                bool keep = false;
                if (v > 0.f) {
                    float lm = v;
                    if (i >= 2)     lm = fmaxf(lm, c[i - 2]);
                    if (i >= 1)     lm = fmaxf(lm, c[i - 1]);
                    if (i + 1 < NL) lm = fmaxf(lm, c[i + 1]);
                    if (i + 2 < NL) lm = fmaxf(lm, c[i + 2]);
                    keep = (v == lm);
                }
                if (!keep) {  // cp == 0 at this position
                    emit_one(b, r, i, 0.f, window_, offset, out);
                    ++r;
                }
            }
        }
    }
}

// ---------------------------------------------------------------------------
extern "C" void kernel_launch(void* const* d_in, const int* in_sizes, int n_in,
                              void* d_out, int out_size, void* d_ws, size_t ws_size,
                              hipStream_t stream)
{
    const float* x   = (const float*)d_in[0];
    const float* sal = (const float*)d_in[1];
    const float* Wc  = (const float*)d_in[2];
    const float* bc  = (const float*)d_in[3];
    const float* Ww  = (const float*)d_in[4];
    const float* bw  = (const float*)d_in[5];
    const float* Wo  = (const float*)d_in[6];
    const float* bo  = (const float*)d_in[7];
    float* out = (float*)d_out;

    float* ws      = (float*)d_ws;
    float* center  = ws;                 // [NB*NL]
    float* window_ = ws + NB * NL;       // [NB*NL]
    float* offset  = ws + 2 * NB * NL;   // [NB*NL]

    proj_kernel<<<NBLOCKS, 256, 0, stream>>>(x, sal, Wc, bc, Ww, bw, Wo, bo,
                                             center, window_, offset);

    topk_kernel<<<NB, 1024, 0, stream>>>(center, window_, offset, out);
}

// Round 3
// 263.698 us; speedup vs baseline: 1.0841x; 1.0580x over previous
//
#include <hip/hip_runtime.h>
#include <stdint.h>

#define NB 32
#define NL 8192
#define ND 1024
#define NTOPK 100
#define CAND_CAP 3072

#define NBLOCKS 1024
#define NWAVES (NBLOCKS * 4)                      // 4096 waves
#define ROWS_PER_WAVE ((NB * NL) / NWAVES)        // 64

// ---------------------------------------------------------------------------
// Kernel 1: fused triple projection.
// Grid-stride row order: wave w handles rows w, w+4096, ... so all resident
// waves read ONE contiguous ~16 MB window sweeping the buffer (DRAM
// row-buffer friendly, copy-like). Weights live in registers; next row is
// prefetched into registers while the current row's dot/reduce runs.
// ---------------------------------------------------------------------------
__global__ __launch_bounds__(256, 4) void proj_kernel(
    const float* __restrict__ x, const float* __restrict__ sal,
    const float* __restrict__ Wc, const float* __restrict__ bc,
    const float* __restrict__ Ww, const float* __restrict__ bw,
    const float* __restrict__ Wo, const float* __restrict__ bo,
    float* __restrict__ center, float* __restrict__ window_,
    float* __restrict__ offset)
{
    const int wid  = (int)(blockIdx.x * 4u + (threadIdx.x >> 6));
    const int lane = (int)(threadIdx.x & 63u);

    const float4* wc4 = (const float4*)Wc;
    const float4* ww4 = (const float4*)Ww;
    const float4* wo4 = (const float4*)Wo;
    const float4* x4  = (const float4*)x;

    // weights in registers (48 VGPRs)
    float4 wc[4], ww[4], wo[4];
#pragma unroll
    for (int j = 0; j < 4; ++j) {
        const int k = lane + 64 * j;
        wc[j] = wc4[k];
        ww[j] = ww4[k];
        wo[j] = wo4[k];
    }
    const float bcs = bc[0], bws = bw[0], bos = bo[0];

    int row = wid;
    float4 cur[4];
#pragma unroll
    for (int j = 0; j < 4; ++j) cur[j] = x4[(size_t)row * (ND / 4) + lane + 64 * j];
    float sal_cur = sal[row];

    for (int r = 0; r < ROWS_PER_WAVE; ++r) {
        const int nrow = row + NWAVES;
        float4 nxt[4];
        float sal_nxt = 0.f;
        if (r + 1 < ROWS_PER_WAVE) {
#pragma unroll
            for (int j = 0; j < 4; ++j)
                nxt[j] = x4[(size_t)nrow * (ND / 4) + lane + 64 * j];
            sal_nxt = sal[nrow];
        } else {
#pragma unroll
            for (int j = 0; j < 4; ++j) nxt[j] = make_float4(0.f, 0.f, 0.f, 0.f);
        }

        float dc = 0.f, dw = 0.f, dz = 0.f;
#pragma unroll
        for (int j = 0; j < 4; ++j) {
            dc += cur[j].x * wc[j].x + cur[j].y * wc[j].y + cur[j].z * wc[j].z + cur[j].w * wc[j].w;
            dw += cur[j].x * ww[j].x + cur[j].y * ww[j].y + cur[j].z * ww[j].z + cur[j].w * ww[j].w;
            dz += cur[j].x * wo[j].x + cur[j].y * wo[j].y + cur[j].z * wo[j].z + cur[j].w * wo[j].w;
        }
#pragma unroll
        for (int s = 32; s > 0; s >>= 1) {
            dc += __shfl_xor(dc, s, 64);
            dw += __shfl_xor(dw, s, 64);
            dz += __shfl_xor(dz, s, 64);
        }
        // all lanes hold the totals after the butterfly; spread the 3 stores
        if (lane == 0) {
            const float m = (sal_cur >= 0.f) ? 1.f : 0.f;
            center[row] = m / (1.f + expf(-(dc + bcs)));
        } else if (lane == 1) {
            window_[row] = dw + bws;
        } else if (lane == 2) {
            offset[row] = dz + bos;
        }

        row = nrow;
#pragma unroll
        for (int j = 0; j < 4; ++j) cur[j] = nxt[j];
        sal_cur = sal_nxt;
    }
}

// ---------------------------------------------------------------------------
// Kernel 2: per-batch-row NMS + exact top-100 + boundary computation.
// One block (1024 threads) per batch row.
// Key encoding: (float_bits << 32) | (0xFFFFFFFF - idx). For cp >= 0 the float
// bit pattern is monotonic, so uint64 '>' == (value desc, index asc) — exactly
// jax.lax.top_k tie-breaking.
// ---------------------------------------------------------------------------
__device__ __forceinline__ void emit_one(
    int b, int rank, int idx, float val,
    const float* __restrict__ window_, const float* __restrict__ offset,
    float* __restrict__ out)
{
    const float off = offset[b * NL + idx];
    float win = window_[b * NL + idx];
    win = fmaxf(win, 0.f);
    float c = (float)idx + off;
    c = fminf(fmaxf(c, 0.f), (float)(NL - 1));
    float s = fminf(fmaxf(c - 0.5f * win, 0.f), (float)(NL - 1)) * 2.0f;
    float e = fminf(fmaxf(c + 0.5f * win, 0.f), (float)(NL - 1)) * 2.0f + 2.0f;
    float* o = out + ((size_t)b * NTOPK + rank) * 3;
    o[0] = s;
    o[1] = e;
    o[2] = val;
}

__global__ __launch_bounds__(1024) void topk_kernel(
    const float* __restrict__ center, const float* __restrict__ window_,
    const float* __restrict__ offset, float* __restrict__ out)
{
    __shared__ float c[NL];                       // 32 KB
    __shared__ unsigned long long cand[CAND_CAP]; // 24 KB
    __shared__ int cnt;

    const int b   = blockIdx.x;
    const int tid = (int)threadIdx.x;

    if (tid == 0) cnt = 0;

#pragma unroll
    for (int k = 0; k < NL / 1024; ++k)
        c[tid + k * 1024] = center[b * NL + tid + k * 1024];
    __syncthreads();

#pragma unroll
    for (int k = 0; k < NL / 1024; ++k) {
        const int i = tid + k * 1024;
        const float v = c[i];
        if (v > 0.f) {
            float lm = v;
            if (i >= 2)      lm = fmaxf(lm, c[i - 2]);
            if (i >= 1)      lm = fmaxf(lm, c[i - 1]);
            if (i + 1 < NL)  lm = fmaxf(lm, c[i + 1]);
            if (i + 2 < NL)  lm = fmaxf(lm, c[i + 2]);
            if (v == lm) {
                const int pos = atomicAdd(&cnt, 1);
                if (pos < CAND_CAP) {
                    const unsigned long long key =
                        ((unsigned long long)__float_as_uint(v) << 32) |
                        (unsigned long long)(0xFFFFFFFFu - (unsigned)i);
                    cand[pos] = key;
                }
            }
        }
    }
    __syncthreads();

    const int C = (cnt < CAND_CAP) ? cnt : CAND_CAP;

    for (int i = tid; i < C; i += 1024) {
        const unsigned long long ki = cand[i];
        int r = 0;
        for (int j = 0; j < C; ++j) r += (cand[j] > ki) ? 1 : 0;
        if (r < NTOPK) {
            const int idx = (int)(0xFFFFFFFFu - (unsigned)(ki & 0xFFFFFFFFull));
            const float val = __uint_as_float((unsigned)(ki >> 32));
            emit_one(b, r, idx, val, window_, offset, out);
        }
    }

    if (C < NTOPK) {
        __syncthreads();
        if (tid == 0) {
            int r = C;
            for (int i = 0; i < NL && r < NTOPK; ++i) {
                const float v = c[i];
                bool keep = false;
                if (v > 0.f) {
                    float lm = v;
                    if (i >= 2)     lm = fmaxf(lm, c[i - 2]);
                    if (i >= 1)     lm = fmaxf(lm, c[i - 1]);
                    if (i + 1 < NL) lm = fmaxf(lm, c[i + 1]);
                    if (i + 2 < NL) lm = fmaxf(lm, c[i + 2]);
                    keep = (v == lm);
                }
                if (!keep) {
                    emit_one(b, r, i, 0.f, window_, offset, out);
                    ++r;
                }
            }
        }
    }
}

// ---------------------------------------------------------------------------
extern "C" void kernel_launch(void* const* d_in, const int* in_sizes, int n_in,
                              void* d_out, int out_size, void* d_ws, size_t ws_size,
                              hipStream_t stream)
{
    const float* x   = (const float*)d_in[0];
    const float* sal = (const float*)d_in[1];
    const float* Wc  = (const float*)d_in[2];
    const float* bc  = (const float*)d_in[3];
    const float* Ww  = (const float*)d_in[4];
    const float* bw  = (const float*)d_in[5];
    const float* Wo  = (const float*)d_in[6];
    const float* bo  = (const float*)d_in[7];
    float* out = (float*)d_out;

    float* ws      = (float*)d_ws;
    float* center  = ws;                 // [NB*NL]
    float* window_ = ws + NB * NL;       // [NB*NL]
    float* offset  = ws + 2 * NB * NL;   // [NB*NL]

    proj_kernel<<<NBLOCKS, 256, 0, stream>>>(x, sal, Wc, bc, Ww, bw, Wo, bo,
                                             center, window_, offset);

    topk_kernel<<<NB, 1024, 0, stream>>>(center, window_, offset, out);
}

// Round 4
// 263.446 us; speedup vs baseline: 1.0852x; 1.0010x over previous
//
#include <hip/hip_runtime.h>
#include <stdint.h>

#define NB 32
#define NL 8192
#define ND 1024
#define NTOPK 100
#define CAND_CAP 3072

#define NBLOCKS 1024
#define NWAVES (NBLOCKS * 4)                      // 4096 waves
#define ROWS_PER_WAVE ((NB * NL) / NWAVES)        // 64

// ---------------------------------------------------------------------------
// Kernel 1: fused triple projection.
// Grid-stride row order (contiguous device-wide sweep) + 3-buffer software
// pipeline: loads for row k+2 are issued before computing row k, so each
// wave keeps ~8KB of reads continuously in flight (Little's-law coverage).
// Weights live in registers. Reduction order identical to R1-R3 (bit-exact).
// ---------------------------------------------------------------------------
__global__ __launch_bounds__(256, 4) void proj_kernel(
    const float* __restrict__ x, const float* __restrict__ sal,
    const float* __restrict__ Wc, const float* __restrict__ bc,
    const float* __restrict__ Ww, const float* __restrict__ bw,
    const float* __restrict__ Wo, const float* __restrict__ bo,
    float* __restrict__ center, float* __restrict__ window_,
    float* __restrict__ offset)
{
    const int wid  = (int)(blockIdx.x * 4u + (threadIdx.x >> 6));
    const int lane = (int)(threadIdx.x & 63u);

    const float4* x4  = (const float4*)x;

    // weights in registers (48 VGPRs)
    float4 wc[4], ww[4], wo[4];
#pragma unroll
    for (int j = 0; j < 4; ++j) {
        const int k = lane + 64 * j;
        wc[j] = ((const float4*)Wc)[k];
        ww[j] = ((const float4*)Ww)[k];
        wo[j] = ((const float4*)Wo)[k];
    }
    const float bcs = bc[0], bws = bw[0], bos = bo[0];

    float4 b0[4], b1[4], b2[4];
    float s0, s1, s2;

#define LOADROW(BUF, SALV, K)                                              \
    {                                                                      \
        const size_t base = (size_t)(wid + (K) * NWAVES) * (ND / 4);       \
        BUF[0] = x4[base + lane];                                          \
        BUF[1] = x4[base + lane + 64];                                     \
        BUF[2] = x4[base + lane + 128];                                    \
        BUF[3] = x4[base + lane + 192];                                    \
        SALV   = sal[wid + (K) * NWAVES];                                  \
    }

#define COMPROW(BUF, SALV, K)                                              \
    {                                                                      \
        float dc = 0.f, dw = 0.f, dz = 0.f;                                \
        _Pragma("unroll")                                                  \
        for (int j = 0; j < 4; ++j) {                                      \
            dc += BUF[j].x * wc[j].x + BUF[j].y * wc[j].y +                \
                  BUF[j].z * wc[j].z + BUF[j].w * wc[j].w;                 \
            dw += BUF[j].x * ww[j].x + BUF[j].y * ww[j].y +                \
                  BUF[j].z * ww[j].z + BUF[j].w * ww[j].w;                 \
            dz += BUF[j].x * wo[j].x + BUF[j].y * wo[j].y +                \
                  BUF[j].z * wo[j].z + BUF[j].w * wo[j].w;                 \
        }                                                                  \
        _Pragma("unroll")                                                  \
        for (int s = 32; s > 0; s >>= 1) {                                 \
            dc += __shfl_xor(dc, s, 64);                                   \
            dw += __shfl_xor(dw, s, 64);                                   \
            dz += __shfl_xor(dz, s, 64);                                   \
        }                                                                  \
        const int row = wid + (K) * NWAVES;                                \
        if (lane == 0) {                                                   \
            const float m = (SALV >= 0.f) ? 1.f : 0.f;                     \
            center[row] = m / (1.f + expf(-(dc + bcs)));                   \
        } else if (lane == 1) {                                            \
            window_[row] = dw + bws;                                       \
        } else if (lane == 2) {                                            \
            offset[row] = dz + bos;                                        \
        }                                                                  \
    }

    LOADROW(b0, s0, 0)
    LOADROW(b1, s1, 1)

    // 21 groups of 3 rows (k = 0..62), buffers rotate b0,b1,b2 statically
    for (int g = 0; g < 21; ++g) {
        const int k = g * 3;
        LOADROW(b2, s2, k + 2)
        COMPROW(b0, s0, k)
        if (k + 3 < ROWS_PER_WAVE) LOADROW(b0, s0, k + 3)
        COMPROW(b1, s1, k + 1)
        if (k + 4 < ROWS_PER_WAVE) LOADROW(b1, s1, k + 4)
        COMPROW(b2, s2, k + 2)
    }
    // tail: k = 63 sits in b0 (loaded at k=61 step)
    COMPROW(b0, s0, 63)

#undef LOADROW
#undef COMPROW
}

// ---------------------------------------------------------------------------
// Kernel 2: per-batch-row NMS + exact top-100 + boundary computation.
// One block (1024 threads) per batch row.
// Key encoding: (float_bits << 32) | (0xFFFFFFFF - idx). For cp >= 0 the float
// bit pattern is monotonic, so uint64 '>' == (value desc, index asc) — exactly
// jax.lax.top_k tie-breaking.
// ---------------------------------------------------------------------------
__device__ __forceinline__ void emit_one(
    int b, int rank, int idx, float val,
    const float* __restrict__ window_, const float* __restrict__ offset,
    float* __restrict__ out)
{
    const float off = offset[b * NL + idx];
    float win = window_[b * NL + idx];
    win = fmaxf(win, 0.f);
    float c = (float)idx + off;
    c = fminf(fmaxf(c, 0.f), (float)(NL - 1));
    float s = fminf(fmaxf(c - 0.5f * win, 0.f), (float)(NL - 1)) * 2.0f;
    float e = fminf(fmaxf(c + 0.5f * win, 0.f), (float)(NL - 1)) * 2.0f + 2.0f;
    float* o = out + ((size_t)b * NTOPK + rank) * 3;
    o[0] = s;
    o[1] = e;
    o[2] = val;
}

__global__ __launch_bounds__(1024) void topk_kernel(
    const float* __restrict__ center, const float* __restrict__ window_,
    const float* __restrict__ offset, float* __restrict__ out)
{
    __shared__ float c[NL];                       // 32 KB
    __shared__ unsigned long long cand[CAND_CAP]; // 24 KB
    __shared__ int cnt;

    const int b   = blockIdx.x;
    const int tid = (int)threadIdx.x;

    if (tid == 0) cnt = 0;

#pragma unroll
    for (int k = 0; k < NL / 1024; ++k)
        c[tid + k * 1024] = center[b * NL + tid + k * 1024];
    __syncthreads();

#pragma unroll
    for (int k = 0; k < NL / 1024; ++k) {
        const int i = tid + k * 1024;
        const float v = c[i];
        if (v > 0.f) {
            float lm = v;
            if (i >= 2)      lm = fmaxf(lm, c[i - 2]);
            if (i >= 1)      lm = fmaxf(lm, c[i - 1]);
            if (i + 1 < NL)  lm = fmaxf(lm, c[i + 1]);
            if (i + 2 < NL)  lm = fmaxf(lm, c[i + 2]);
            if (v == lm) {
                const int pos = atomicAdd(&cnt, 1);
                if (pos < CAND_CAP) {
                    const unsigned long long key =
                        ((unsigned long long)__float_as_uint(v) << 32) |
                        (unsigned long long)(0xFFFFFFFFu - (unsigned)i);
                    cand[pos] = key;
                }
            }
        }
    }
    __syncthreads();

    const int C = (cnt < CAND_CAP) ? cnt : CAND_CAP;

    for (int i = tid; i < C; i += 1024) {
        const unsigned long long ki = cand[i];
        int r = 0;
        for (int j = 0; j < C; ++j) r += (cand[j] > ki) ? 1 : 0;
        if (r < NTOPK) {
            const int idx = (int)(0xFFFFFFFFu - (unsigned)(ki & 0xFFFFFFFFull));
            const float val = __uint_as_float((unsigned)(ki >> 32));
            emit_one(b, r, idx, val, window_, offset, out);
        }
    }

    if (C < NTOPK) {
        __syncthreads();
        if (tid == 0) {
            int r = C;
            for (int i = 0; i < NL && r < NTOPK; ++i) {
                const float v = c[i];
                bool keep = false;
                if (v > 0.f) {
                    float lm = v;
                    if (i >= 2)     lm = fmaxf(lm, c[i - 2]);
                    if (i >= 1)     lm = fmaxf(lm, c[i - 1]);
                    if (i + 1 < NL) lm = fmaxf(lm, c[i + 1]);
                    if (i + 2 < NL) lm = fmaxf(lm, c[i + 2]);
                    keep = (v == lm);
                }
                if (!keep) {
                    emit_one(b, r, i, 0.f, window_, offset, out);
                    ++r;
                }
            }
        }
    }
}

// ---------------------------------------------------------------------------
extern "C" void kernel_launch(void* const* d_in, const int* in_sizes, int n_in,
                              void* d_out, int out_size, void* d_ws, size_t ws_size,
                              hipStream_t stream)
{
    const float* x   = (const float*)d_in[0];
    const float* sal = (const float*)d_in[1];
    const float* Wc  = (const float*)d_in[2];
    const float* bc  = (const float*)d_in[3];
    const float* Ww  = (const float*)d_in[4];
    const float* bw  = (const float*)d_in[5];
    const float* Wo  = (const float*)d_in[6];
    const float* bo  = (const float*)d_in[7];
    float* out = (float*)d_out;

    float* ws      = (float*)d_ws;
    float* center  = ws;                 // [NB*NL]
    float* window_ = ws + NB * NL;       // [NB*NL]
    float* offset  = ws + 2 * NB * NL;   // [NB*NL]

    proj_kernel<<<NBLOCKS, 256, 0, stream>>>(x, sal, Wc, bc, Ww, bw, Wo, bo,
                                             center, window_, offset);

    topk_kernel<<<NB, 1024, 0, stream>>>(center, window_, offset, out);
}

// Round 5
// 222.942 us; speedup vs baseline: 1.2823x; 1.1817x over previous
//
#include <hip/hip_runtime.h>
#include <stdint.h>

#define NB 32
#define NL 8192
#define ND 1024
#define NTOPK 100
#define CAND_CAP 3072
#define SUBCAP 1536

#define NBLOCKS 1024
#define NWAVES (NBLOCKS * 4)                      // 4096 waves
#define ROWS_PER_WAVE ((NB * NL) / NWAVES)        // 64

// ---------------------------------------------------------------------------
// Kernel 1: fused triple projection (UNCHANGED from R4 for attribution).
// ---------------------------------------------------------------------------
__global__ __launch_bounds__(256, 4) void proj_kernel(
    const float* __restrict__ x, const float* __restrict__ sal,
    const float* __restrict__ Wc, const float* __restrict__ bc,
    const float* __restrict__ Ww, const float* __restrict__ bw,
    const float* __restrict__ Wo, const float* __restrict__ bo,
    float* __restrict__ center, float* __restrict__ window_,
    float* __restrict__ offset)
{
    const int wid  = (int)(blockIdx.x * 4u + (threadIdx.x >> 6));
    const int lane = (int)(threadIdx.x & 63u);

    const float4* x4  = (const float4*)x;

    float4 wc[4], ww[4], wo[4];
#pragma unroll
    for (int j = 0; j < 4; ++j) {
        const int k = lane + 64 * j;
        wc[j] = ((const float4*)Wc)[k];
        ww[j] = ((const float4*)Ww)[k];
        wo[j] = ((const float4*)Wo)[k];
    }
    const float bcs = bc[0], bws = bw[0], bos = bo[0];

    float4 b0[4], b1[4], b2[4];
    float s0, s1, s2;

#define LOADROW(BUF, SALV, K)                                              \
    {                                                                      \
        const size_t base = (size_t)(wid + (K) * NWAVES) * (ND / 4);       \
        BUF[0] = x4[base + lane];                                          \
        BUF[1] = x4[base + lane + 64];                                     \
        BUF[2] = x4[base + lane + 128];                                    \
        BUF[3] = x4[base + lane + 192];                                    \
        SALV   = sal[wid + (K) * NWAVES];                                  \
    }

#define COMPROW(BUF, SALV, K)                                              \
    {                                                                      \
        float dc = 0.f, dw = 0.f, dz = 0.f;                                \
        _Pragma("unroll")                                                  \
        for (int j = 0; j < 4; ++j) {                                      \
            dc += BUF[j].x * wc[j].x + BUF[j].y * wc[j].y +                \
                  BUF[j].z * wc[j].z + BUF[j].w * wc[j].w;                 \
            dw += BUF[j].x * ww[j].x + BUF[j].y * ww[j].y +                \
                  BUF[j].z * ww[j].z + BUF[j].w * ww[j].w;                 \
            dz += BUF[j].x * wo[j].x + BUF[j].y * wo[j].y +                \
                  BUF[j].z * wo[j].z + BUF[j].w * wo[j].w;                 \
        }                                                                  \
        _Pragma("unroll")                                                  \
        for (int s = 32; s > 0; s >>= 1) {                                 \
            dc += __shfl_xor(dc, s, 64);                                   \
            dw += __shfl_xor(dw, s, 64);                                   \
            dz += __shfl_xor(dz, s, 64);                                   \
        }                                                                  \
        const int row = wid + (K) * NWAVES;                                \
        if (lane == 0) {                                                   \
            const float m = (SALV >= 0.f) ? 1.f : 0.f;                     \
            center[row] = m / (1.f + expf(-(dc + bcs)));                   \
        } else if (lane == 1) {                                            \
            window_[row] = dw + bws;                                       \
        } else if (lane == 2) {                                            \
            offset[row] = dz + bos;                                        \
        }                                                                  \
    }

    LOADROW(b0, s0, 0)
    LOADROW(b1, s1, 1)

    for (int g = 0; g < 21; ++g) {
        const int k = g * 3;
        LOADROW(b2, s2, k + 2)
        COMPROW(b0, s0, k)
        if (k + 3 < ROWS_PER_WAVE) LOADROW(b0, s0, k + 3)
        COMPROW(b1, s1, k + 1)
        if (k + 4 < ROWS_PER_WAVE) LOADROW(b1, s1, k + 4)
        COMPROW(b2, s2, k + 2)
    }
    COMPROW(b0, s0, 63)

#undef LOADROW
#undef COMPROW
}

// ---------------------------------------------------------------------------
// Kernel 2: per-batch-row NMS + exact top-100 via histogram threshold.
// Key encoding unchanged: (valbits<<32)|(0xFFFFFFFF-idx); uint64 '>' ==
// (value desc, index asc) == jax.lax.top_k order. The histogram only
// PRE-FILTERS to the candidates that can hold rank<100; exact all-pairs rank
// runs on that small subset, so results are bit-identical to the full path.
// ---------------------------------------------------------------------------
__device__ __forceinline__ void emit_one(
    int b, int rank, int idx, float val,
    const float* __restrict__ window_, const float* __restrict__ offset,
    float* __restrict__ out)
{
    const float off = offset[b * NL + idx];
    float win = window_[b * NL + idx];
    win = fmaxf(win, 0.f);
    float c = (float)idx + off;
    c = fminf(fmaxf(c, 0.f), (float)(NL - 1));
    float s = fminf(fmaxf(c - 0.5f * win, 0.f), (float)(NL - 1)) * 2.0f;
    float e = fminf(fmaxf(c + 0.5f * win, 0.f), (float)(NL - 1)) * 2.0f + 2.0f;
    float* o = out + ((size_t)b * NTOPK + rank) * 3;
    o[0] = s;
    o[1] = e;
    o[2] = val;
}

__global__ __launch_bounds__(1024) void topk_kernel(
    const float* __restrict__ center, const float* __restrict__ window_,
    const float* __restrict__ offset, float* __restrict__ out)
{
    __shared__ __align__(16) float c[NL];          // 32 KB (aliased as subk in subset path)
    __shared__ unsigned long long cand[CAND_CAP];  // 24 KB
    __shared__ int hist[256];                      // 1 KB
    __shared__ unsigned short sel[SUBCAP];         // 3 KB
    __shared__ int cnt, scnt, sB, sAbove, sTH;

    const int b   = blockIdx.x;
    const int tid = (int)threadIdx.x;

    if (tid == 0) { cnt = 0; scnt = 0; }

    // stage center row into LDS (coalesced)
#pragma unroll
    for (int k = 0; k < NL / 1024; ++k)
        c[tid + k * 1024] = center[b * NL + tid + k * 1024];
    __syncthreads();

    // NMS: keep i iff c[i] > 0 and c[i] == max over window [i-2, i+2]
#pragma unroll
    for (int k = 0; k < NL / 1024; ++k) {
        const int i = tid + k * 1024;
        const float v = c[i];
        if (v > 0.f) {
            float lm = v;
            if (i >= 2)      lm = fmaxf(lm, c[i - 2]);
            if (i >= 1)      lm = fmaxf(lm, c[i - 1]);
            if (i + 1 < NL)  lm = fmaxf(lm, c[i + 1]);
            if (i + 2 < NL)  lm = fmaxf(lm, c[i + 2]);
            if (v == lm) {
                const int pos = atomicAdd(&cnt, 1);
                if (pos < CAND_CAP) {
                    const unsigned long long key =
                        ((unsigned long long)__float_as_uint(v) << 32) |
                        (unsigned long long)(0xFFFFFFFFu - (unsigned)i);
                    cand[pos] = key;
                }
            }
        }
    }
    __syncthreads();

    const int C = (cnt < CAND_CAP) ? cnt : CAND_CAP;
    bool fullpath = (C <= 2 * NTOPK);   // small C: all-pairs is already cheap

    if (!fullpath) {
        // ---- coarse histogram on value-bits >> 22 (values in (0,1): bin<=253)
        for (int i = tid; i < 256; i += 1024) hist[i] = 0;
        __syncthreads();
        for (int i = tid; i < C; i += 1024) {
            const unsigned u = (unsigned)(cand[i] >> 32);
            atomicAdd(&hist[u >> 22], 1);
        }
        __syncthreads();
        if (tid == 0) {
            int acc = 0, B = 0, above = 0;
            for (int bb = 255; bb >= 0; --bb) {
                acc += hist[bb];
                if (acc >= NTOPK) { B = bb; above = acc - hist[bb]; break; }
            }
            sB = B; sAbove = above;
        }
        __syncthreads();
        const int B = sB, above = sAbove;

        // ---- fine histogram on bits (u>>14)&0xFF within coarse bin B
        for (int i = tid; i < 256; i += 1024) hist[i] = 0;
        __syncthreads();
        for (int i = tid; i < C; i += 1024) {
            const unsigned u = (unsigned)(cand[i] >> 32);
            if ((int)(u >> 22) == B) atomicAdd(&hist[(u >> 14) & 0xFF], 1);
        }
        __syncthreads();
        if (tid == 0) {
            const int need = NTOPK - above;
            int acc = 0, F = 0;
            for (int fb = 255; fb >= 0; --fb) {
                acc += hist[fb];
                if (acc >= need) { F = fb; break; }
            }
            sTH = (B << 22) | (F << 14);   // all top-100 have u >= sTH
        }
        __syncthreads();
        const unsigned TH = (unsigned)sTH;

        // ---- collect subset {u >= TH} (>=100 members, expected ~100-200)
        for (int i = tid; i < C; i += 1024) {
            const unsigned u = (unsigned)(cand[i] >> 32);
            if (u >= TH) {
                const int p = atomicAdd(&scnt, 1);
                if (p < SUBCAP) sel[p] = (unsigned short)i;
            }
        }
        __syncthreads();

        if (scnt > SUBCAP) {
            fullpath = true;    // pathological tie pile-up: exact fallback
        } else {
            const int S = scnt;
            // c[] is dead in this branch (C>200 => zero-fill never needed):
            // reuse its LDS as a compact key array for fast broadcast scans.
            unsigned long long* subk = (unsigned long long*)c;
            for (int s = tid; s < S; s += 1024) subk[s] = cand[sel[s]];
            __syncthreads();
            for (int s = tid; s < S; s += 1024) {
                const unsigned long long ki = subk[s];
                int r = 0;
                for (int j = 0; j < S; ++j) r += (subk[j] > ki) ? 1 : 0;
                if (r < NTOPK) {
                    const int idx = (int)(0xFFFFFFFFu - (unsigned)(ki & 0xFFFFFFFFull));
                    const float val = __uint_as_float((unsigned)(ki >> 32));
                    emit_one(b, r, idx, val, window_, offset, out);
                }
            }
        }
    }

    if (fullpath) {
        // exact rank over all C candidates (cheap when C small; correctness
        // fallback otherwise)
        for (int i = tid; i < C; i += 1024) {
            const unsigned long long ki = cand[i];
            int r = 0;
            for (int j = 0; j < C; ++j) r += (cand[j] > ki) ? 1 : 0;
            if (r < NTOPK) {
                const int idx = (int)(0xFFFFFFFFu - (unsigned)(ki & 0xFFFFFFFFull));
                const float val = __uint_as_float((unsigned)(ki >> 32));
                emit_one(b, r, idx, val, window_, offset, out);
            }
        }
        // fewer than 100 positives: fill with cp==0 entries, index ascending
        if (C < NTOPK) {
            __syncthreads();
            if (tid == 0) {
                int r = C;
                for (int i = 0; i < NL && r < NTOPK; ++i) {
                    const float v = c[i];
                    bool keep = false;
                    if (v > 0.f) {
                        float lm = v;
                        if (i >= 2)     lm = fmaxf(lm, c[i - 2]);
                        if (i >= 1)     lm = fmaxf(lm, c[i - 1]);
                        if (i + 1 < NL) lm = fmaxf(lm, c[i + 1]);
                        if (i + 2 < NL) lm = fmaxf(lm, c[i + 2]);
                        keep = (v == lm);
                    }
                    if (!keep) {
                        emit_one(b, r, i, 0.f, window_, offset, out);
                        ++r;
                    }
                }
            }
        }
    }
}

// ---------------------------------------------------------------------------
extern "C" void kernel_launch(void* const* d_in, const int* in_sizes, int n_in,
                              void* d_out, int out_size, void* d_ws, size_t ws_size,
                              hipStream_t stream)
{
    const float* x   = (const float*)d_in[0];
    const float* sal = (const float*)d_in[1];
    const float* Wc  = (const float*)d_in[2];
    const float* bc  = (const float*)d_in[3];
    const float* Ww  = (const float*)d_in[4];
    const float* bw  = (const float*)d_in[5];
    const float* Wo  = (const float*)d_in[6];
    const float* bo  = (const float*)d_in[7];
    float* out = (float*)d_out;

    float* ws      = (float*)d_ws;
    float* center  = ws;                 // [NB*NL]
    float* window_ = ws + NB * NL;       // [NB*NL]
    float* offset  = ws + 2 * NB * NL;   // [NB*NL]

    proj_kernel<<<NBLOCKS, 256, 0, stream>>>(x, sal, Wc, bc, Ww, bw, Wo, bo,
                                             center, window_, offset);

    topk_kernel<<<NB, 1024, 0, stream>>>(center, window_, offset, out);
}

// Round 6
// 214.978 us; speedup vs baseline: 1.3298x; 1.0370x over previous
//
#include <hip/hip_runtime.h>
#include <stdint.h>

#define NB 32
#define NL 8192
#define ND 1024
#define NTOPK 100
#define CAND_CAP 3072
#define SUBCAP 1536

#define NBLOCKS 1024
#define NWAVES (NBLOCKS * 4)                      // 4096 waves
#define ROWS_PER_WAVE ((NB * NL) / NWAVES)        // 64

// ---------------------------------------------------------------------------
// Kernel 1: fused triple projection (UNCHANGED from R4/R5 for attribution).
// ---------------------------------------------------------------------------
__global__ __launch_bounds__(256, 4) void proj_kernel(
    const float* __restrict__ x, const float* __restrict__ sal,
    const float* __restrict__ Wc, const float* __restrict__ bc,
    const float* __restrict__ Ww, const float* __restrict__ bw,
    const float* __restrict__ Wo, const float* __restrict__ bo,
    float* __restrict__ center, float* __restrict__ window_,
    float* __restrict__ offset)
{
    const int wid  = (int)(blockIdx.x * 4u + (threadIdx.x >> 6));
    const int lane = (int)(threadIdx.x & 63u);

    const float4* x4  = (const float4*)x;

    float4 wc[4], ww[4], wo[4];
#pragma unroll
    for (int j = 0; j < 4; ++j) {
        const int k = lane + 64 * j;
        wc[j] = ((const float4*)Wc)[k];
        ww[j] = ((const float4*)Ww)[k];
        wo[j] = ((const float4*)Wo)[k];
    }
    const float bcs = bc[0], bws = bw[0], bos = bo[0];

    float4 b0[4], b1[4], b2[4];
    float s0, s1, s2;

#define LOADROW(BUF, SALV, K)                                              \
    {                                                                      \
        const size_t base = (size_t)(wid + (K) * NWAVES) * (ND / 4);       \
        BUF[0] = x4[base + lane];                                          \
        BUF[1] = x4[base + lane + 64];                                     \
        BUF[2] = x4[base + lane + 128];                                    \
        BUF[3] = x4[base + lane + 192];                                    \
        SALV   = sal[wid + (K) * NWAVES];                                  \
    }

#define COMPROW(BUF, SALV, K)                                              \
    {                                                                      \
        float dc = 0.f, dw = 0.f, dz = 0.f;                                \
        _Pragma("unroll")                                                  \
        for (int j = 0; j < 4; ++j) {                                      \
            dc += BUF[j].x * wc[j].x + BUF[j].y * wc[j].y +                \
                  BUF[j].z * wc[j].z + BUF[j].w * wc[j].w;                 \
            dw += BUF[j].x * ww[j].x + BUF[j].y * ww[j].y +                \
                  BUF[j].z * ww[j].z + BUF[j].w * ww[j].w;                 \
            dz += BUF[j].x * wo[j].x + BUF[j].y * wo[j].y +                \
                  BUF[j].z * wo[j].z + BUF[j].w * wo[j].w;                 \
        }                                                                  \
        _Pragma("unroll")                                                  \
        for (int s = 32; s > 0; s >>= 1) {                                 \
            dc += __shfl_xor(dc, s, 64);                                   \
            dw += __shfl_xor(dw, s, 64);                                   \
            dz += __shfl_xor(dz, s, 64);                                   \
        }                                                                  \
        const int row = wid + (K) * NWAVES;                                \
        if (lane == 0) {                                                   \
            const float m = (SALV >= 0.f) ? 1.f : 0.f;                     \
            center[row] = m / (1.f + expf(-(dc + bcs)));                   \
        } else if (lane == 1) {                                            \
            window_[row] = dw + bws;                                       \
        } else if (lane == 2) {                                            \
            offset[row] = dz + bos;                                        \
        }                                                                  \
    }

    LOADROW(b0, s0, 0)
    LOADROW(b1, s1, 1)

    for (int g = 0; g < 21; ++g) {
        const int k = g * 3;
        LOADROW(b2, s2, k + 2)
        COMPROW(b0, s0, k)
        if (k + 3 < ROWS_PER_WAVE) LOADROW(b0, s0, k + 3)
        COMPROW(b1, s1, k + 1)
        if (k + 4 < ROWS_PER_WAVE) LOADROW(b1, s1, k + 4)
        COMPROW(b2, s2, k + 2)
    }
    COMPROW(b0, s0, 63)

#undef LOADROW
#undef COMPROW
}

// ---------------------------------------------------------------------------
// Kernel 2: per-batch-row NMS + exact top-100 via histogram threshold.
// All serial scalar phases parallelized:
//  - threshold find = one-wave shfl suffix-scan over 256 bins
//  - candidate/subset push = wave-aggregated ballot+popc, 1 atomic/wave
// Key encoding: (valbits<<32)|(0xFFFFFFFF-idx); uint64 '>' == (value desc,
// index asc) == jax.lax.top_k order. Results bit-identical to full path.
// ---------------------------------------------------------------------------
__device__ __forceinline__ void emit_one(
    int b, int rank, int idx, float val,
    const float* __restrict__ window_, const float* __restrict__ offset,
    float* __restrict__ out)
{
    const float off = offset[b * NL + idx];
    float win = window_[b * NL + idx];
    win = fmaxf(win, 0.f);
    float c = (float)idx + off;
    c = fminf(fmaxf(c, 0.f), (float)(NL - 1));
    float s = fminf(fmaxf(c - 0.5f * win, 0.f), (float)(NL - 1)) * 2.0f;
    float e = fminf(fmaxf(c + 0.5f * win, 0.f), (float)(NL - 1)) * 2.0f + 2.0f;
    float* o = out + ((size_t)b * NTOPK + rank) * 3;
    o[0] = s;
    o[1] = e;
    o[2] = val;
}

// one-wave suffix-threshold: find B = max bin with suffix_sum(B) >= K,
// above = suffix_sum(B+1). hist[256] in LDS; executed by wave 0.
__device__ __forceinline__ void wave_threshold(
    const int* hist, int K, int ln, int* outB, int* outAbove)
{
    const int h0 = hist[4 * ln + 0], h1 = hist[4 * ln + 1];
    const int h2 = hist[4 * ln + 2], h3 = hist[4 * ln + 3];
    int S = h0 + h1 + h2 + h3;
#pragma unroll
    for (int d = 1; d < 64; d <<= 1) {
        const int t = __shfl_down(S, d, 64);
        if (ln + d < 64) S += t;
    }
    int Snext = __shfl_down(S, 1, 64);
    if (ln == 63) Snext = 0;
    if (S >= K && Snext < K) {          // exactly one lane
        int acc = Snext, B = 4 * ln, ab = Snext;
        // bins within lane, high to low: 3,2,1,0
        if (acc + h3 >= K)                      { B = 4 * ln + 3; ab = acc; }
        else if (acc + h3 + h2 >= K)            { B = 4 * ln + 2; ab = acc + h3; }
        else if (acc + h3 + h2 + h1 >= K)       { B = 4 * ln + 1; ab = acc + h3 + h2; }
        else                                    { B = 4 * ln + 0; ab = acc + h3 + h2 + h1; }
        *outB = B; *outAbove = ab;
    }
}

__global__ __launch_bounds__(1024) void topk_kernel(
    const float* __restrict__ center, const float* __restrict__ window_,
    const float* __restrict__ offset, float* __restrict__ out)
{
    __shared__ __align__(16) float c[NL];          // 32 KB (aliased as subk)
    __shared__ unsigned long long cand[CAND_CAP];  // 24 KB
    __shared__ int hist[256];                      // 1 KB
    __shared__ int cnt, scnt, sB, sAbove, sTH;

    const int b   = blockIdx.x;
    const int tid = (int)threadIdx.x;
    const int wv  = tid >> 6;
    const int ln  = tid & 63;

    if (tid == 0) { cnt = 0; scnt = 0; }

    // stage center row into LDS (float4, coalesced)
    {
        const float4* src = (const float4*)(center + b * NL);
        float4* dst = (float4*)c;
#pragma unroll
        for (int k = 0; k < NL / 4096; ++k)
            dst[tid + k * 1024] = src[tid + k * 1024];
    }
    __syncthreads();

    // NMS: keep i iff c[i] > 0 and c[i] == max over window [i-2,i+2].
    // Wave-aggregated push: one atomic per wave.
#pragma unroll
    for (int k = 0; k < NL / 1024; ++k) {
        const int i = tid + k * 1024;
        const float v = c[i];
        float lm = v;
        if (i >= 2)      lm = fmaxf(lm, c[i - 2]);
        if (i >= 1)      lm = fmaxf(lm, c[i - 1]);
        if (i + 1 < NL)  lm = fmaxf(lm, c[i + 1]);
        if (i + 2 < NL)  lm = fmaxf(lm, c[i + 2]);
        const bool keep = (v > 0.f) && (v == lm);
        const unsigned long long mask = __ballot(keep);
        int base = 0;
        if (ln == 0 && mask) base = atomicAdd(&cnt, __popcll(mask));
        base = __shfl(base, 0, 64);
        if (keep) {
            const int pos = base + __popcll(mask & ((1ull << ln) - 1ull));
            if (pos < CAND_CAP) {
                cand[pos] = ((unsigned long long)__float_as_uint(v) << 32) |
                            (unsigned long long)(0xFFFFFFFFu - (unsigned)i);
            }
        }
    }
    __syncthreads();

    const int C = (cnt < CAND_CAP) ? cnt : CAND_CAP;
    bool fullpath = (C <= 2 * NTOPK);

    if (!fullpath) {
        // ---- coarse histogram on value-bits >> 22
        if (tid < 256) hist[tid] = 0;
        __syncthreads();
        for (int i = tid; i < C; i += 1024)
            atomicAdd(&hist[(unsigned)(cand[i] >> 32) >> 22], 1);
        __syncthreads();
        if (wv == 0) wave_threshold(hist, NTOPK, ln, &sB, &sAbove);
        __syncthreads();
        const int B = sB, above = sAbove;

        // ---- fine histogram on bits (u>>14)&0xFF within coarse bin B
        if (tid < 256) hist[tid] = 0;
        __syncthreads();
        for (int i = tid; i < C; i += 1024) {
            const unsigned u = (unsigned)(cand[i] >> 32);
            if ((int)(u >> 22) == B) atomicAdd(&hist[(u >> 14) & 0xFF], 1);
        }
        __syncthreads();
        if (wv == 0) {
            int F, dummy;
            F = 0; dummy = 0;
            wave_threshold(hist, NTOPK - above, ln, &F, &dummy);
            // the writing lane publishes TH
            // (wave_threshold writes via pointer only on one lane)
            if (F != 0 || dummy != 0 || true) { /* no-op; publish below */ }
            // publish: the lane that set F writes sTH. Re-derive: only one
            // lane wrote F; others hold 0. Use max-reduce to broadcast.
            int th = (F << 14) | 0;
            th = (F == 0 && dummy == 0) ? 0 : th;   // non-writer lanes hold 0
#pragma unroll
            for (int d = 1; d < 64; d <<= 1) th |= __shfl_xor(th, d, 64);
            if (ln == 0) sTH = (B << 22) | th;
        }
        __syncthreads();
        const unsigned TH = (unsigned)sTH;

        // ---- collect subset {u >= TH} directly into subk (aliases c, dead
        // here since C > 200 means the zero-fill path can never trigger)
        unsigned long long* subk = (unsigned long long*)c;
        for (int i = tid; i < C; i += 1024) {
            const unsigned long long ki = cand[i];
            const bool sel = ((unsigned)(ki >> 32) >= TH);
            const unsigned long long mask = __ballot(sel);
            int base = 0;
            if (ln == 0 && mask) base = atomicAdd(&scnt, __popcll(mask));
            base = __shfl(base, 0, 64);
            if (sel) {
                const int p = base + __popcll(mask & ((1ull << ln) - 1ull));
                if (p < SUBCAP) subk[p] = ki;
            }
        }
        __syncthreads();

        if (scnt > SUBCAP) {
            fullpath = true;    // pathological tie pile-up: exact fallback
        } else {
            const int S = scnt;
            for (int i = tid; i < S; i += 1024) {
                const unsigned long long ki = subk[i];
                int r = 0;
                for (int j = 0; j < S; ++j) r += (subk[j] > ki) ? 1 : 0;
                if (r < NTOPK) {
                    const int idx = (int)(0xFFFFFFFFu - (unsigned)(ki & 0xFFFFFFFFull));
                    const float val = __uint_as_float((unsigned)(ki >> 32));
                    emit_one(b, r, idx, val, window_, offset, out);
                }
            }
        }
    }

    if (fullpath) {
        for (int i = tid; i < C; i += 1024) {
            const unsigned long long ki = cand[i];
            int r = 0;
            for (int j = 0; j < C; ++j) r += (cand[j] > ki) ? 1 : 0;
            if (r < NTOPK) {
                const int idx = (int)(0xFFFFFFFFu - (unsigned)(ki & 0xFFFFFFFFull));
                const float val = __uint_as_float((unsigned)(ki >> 32));
                emit_one(b, r, idx, val, window_, offset, out);
            }
        }
        // fewer than 100 positives: fill with cp==0 entries, index ascending
        if (C < NTOPK) {
            __syncthreads();
            if (tid == 0) {
                int r = C;
                for (int i = 0; i < NL && r < NTOPK; ++i) {
                    const float v = c[i];
                    bool keep = false;
                    if (v > 0.f) {
                        float lm = v;
                        if (i >= 2)     lm = fmaxf(lm, c[i - 2]);
                        if (i >= 1)     lm = fmaxf(lm, c[i - 1]);
                        if (i + 1 < NL) lm = fmaxf(lm, c[i + 1]);
                        if (i + 2 < NL) lm = fmaxf(lm, c[i + 2]);
                        keep = (v == lm);
                    }
                    if (!keep) {
                        emit_one(b, r, i, 0.f, window_, offset, out);
                        ++r;
                    }
                }
            }
        }
    }
}

// ---------------------------------------------------------------------------
extern "C" void kernel_launch(void* const* d_in, const int* in_sizes, int n_in,
                              void* d_out, int out_size, void* d_ws, size_t ws_size,
                              hipStream_t stream)
{
    const float* x   = (const float*)d_in[0];
    const float* sal = (const float*)d_in[1];
    const float* Wc  = (const float*)d_in[2];
    const float* bc  = (const float*)d_in[3];
    const float* Ww  = (const float*)d_in[4];
    const float* bw  = (const float*)d_in[5];
    const float* Wo  = (const float*)d_in[6];
    const float* bo  = (const float*)d_in[7];
    float* out = (float*)d_out;

    float* ws      = (float*)d_ws;
    float* center  = ws;                 // [NB*NL]
    float* window_ = ws + NB * NL;       // [NB*NL]
    float* offset  = ws + 2 * NB * NL;   // [NB*NL]

    proj_kernel<<<NBLOCKS, 256, 0, stream>>>(x, sal, Wc, bc, Ww, bw, Wo, bo,
                                             center, window_, offset);

    topk_kernel<<<NB, 1024, 0, stream>>>(center, window_, offset, out);
}

// Round 8
// 199.075 us; speedup vs baseline: 1.4361x; 1.0799x over previous
//
#include <hip/hip_runtime.h>
#include <stdint.h>

#define NB 32
#define NL 8192
#define ND 1024
#define NTOPK 100
#define CAND_CAP 3072
#define SUBCAP 1536

#define NBLOCKS 1024
#define NWAVES (NBLOCKS * 4)                      // 4096 waves
#define ROWS_PER_WAVE ((NB * NL) / NWAVES)        // 64

typedef float fvec4 __attribute__((ext_vector_type(4)));   // native vector:
// __builtin_nontemporal_load requires a non-struct vector element type.

// ---------------------------------------------------------------------------
// Kernel 1: fused triple projection. R6 structure; x/sal loads are
// NONTEMPORAL (nt) — each byte is read exactly once, so L2 allocation is
// pure overhead. Weights stay cached + hoisted to registers.
// ---------------------------------------------------------------------------
__global__ __launch_bounds__(256, 4) void proj_kernel(
    const float* __restrict__ x, const float* __restrict__ sal,
    const float* __restrict__ Wc, const float* __restrict__ bc,
    const float* __restrict__ Ww, const float* __restrict__ bw,
    const float* __restrict__ Wo, const float* __restrict__ bo,
    float* __restrict__ center, float* __restrict__ window_,
    float* __restrict__ offset)
{
    const int wid  = (int)(blockIdx.x * 4u + (threadIdx.x >> 6));
    const int lane = (int)(threadIdx.x & 63u);

    const fvec4* x4 = (const fvec4*)x;

    fvec4 wc[4], ww[4], wo[4];
#pragma unroll
    for (int j = 0; j < 4; ++j) {
        const int k = lane + 64 * j;
        wc[j] = ((const fvec4*)Wc)[k];
        ww[j] = ((const fvec4*)Ww)[k];
        wo[j] = ((const fvec4*)Wo)[k];
    }
    const float bcs = bc[0], bws = bw[0], bos = bo[0];

    fvec4 b0[4], b1[4], b2[4];
    float s0, s1, s2;

#define LOADROW(BUF, SALV, K)                                              \
    {                                                                      \
        const size_t base = (size_t)(wid + (K) * NWAVES) * (ND / 4);       \
        BUF[0] = __builtin_nontemporal_load(&x4[base + lane]);             \
        BUF[1] = __builtin_nontemporal_load(&x4[base + lane + 64]);        \
        BUF[2] = __builtin_nontemporal_load(&x4[base + lane + 128]);       \
        BUF[3] = __builtin_nontemporal_load(&x4[base + lane + 192]);       \
        SALV   = __builtin_nontemporal_load(&sal[wid + (K) * NWAVES]);     \
    }

#define COMPROW(BUF, SALV, K)                                              \
    {                                                                      \
        float dc = 0.f, dw = 0.f, dz = 0.f;                                \
        _Pragma("unroll")                                                  \
        for (int j = 0; j < 4; ++j) {                                      \
            dc += BUF[j].x * wc[j].x + BUF[j].y * wc[j].y +                \
                  BUF[j].z * wc[j].z + BUF[j].w * wc[j].w;                 \
            dw += BUF[j].x * ww[j].x + BUF[j].y * ww[j].y +                \
                  BUF[j].z * ww[j].z + BUF[j].w * ww[j].w;                 \
            dz += BUF[j].x * wo[j].x + BUF[j].y * wo[j].y +                \
                  BUF[j].z * wo[j].z + BUF[j].w * wo[j].w;                 \
        }                                                                  \
        _Pragma("unroll")                                                  \
        for (int s = 32; s > 0; s >>= 1) {                                 \
            dc += __shfl_xor(dc, s, 64);                                   \
            dw += __shfl_xor(dw, s, 64);                                   \
            dz += __shfl_xor(dz, s, 64);                                   \
        }                                                                  \
        const int row = wid + (K) * NWAVES;                                \
        if (lane == 0) {                                                   \
            const float m = (SALV >= 0.f) ? 1.f : 0.f;                     \
            center[row] = m / (1.f + expf(-(dc + bcs)));                   \
        } else if (lane == 1) {                                            \
            window_[row] = dw + bws;                                       \
        } else if (lane == 2) {                                            \
            offset[row] = dz + bos;                                        \
        }                                                                  \
    }

    LOADROW(b0, s0, 0)
    LOADROW(b1, s1, 1)

    for (int g = 0; g < 21; ++g) {
        const int k = g * 3;
        LOADROW(b2, s2, k + 2)
        COMPROW(b0, s0, k)
        if (k + 3 < ROWS_PER_WAVE) LOADROW(b0, s0, k + 3)
        COMPROW(b1, s1, k + 1)
        if (k + 4 < ROWS_PER_WAVE) LOADROW(b1, s1, k + 4)
        COMPROW(b2, s2, k + 2)
    }
    COMPROW(b0, s0, 63)

#undef LOADROW
#undef COMPROW
}

// ---------------------------------------------------------------------------
// Kernel 2: per-batch-row NMS + exact top-100 via histogram threshold
// (UNCHANGED from R6).
// ---------------------------------------------------------------------------
__device__ __forceinline__ void emit_one(
    int b, int rank, int idx, float val,
    const float* __restrict__ window_, const float* __restrict__ offset,
    float* __restrict__ out)
{
    const float off = offset[b * NL + idx];
    float win = window_[b * NL + idx];
    win = fmaxf(win, 0.f);
    float c = (float)idx + off;
    c = fminf(fmaxf(c, 0.f), (float)(NL - 1));
    float s = fminf(fmaxf(c - 0.5f * win, 0.f), (float)(NL - 1)) * 2.0f;
    float e = fminf(fmaxf(c + 0.5f * win, 0.f), (float)(NL - 1)) * 2.0f + 2.0f;
    float* o = out + ((size_t)b * NTOPK + rank) * 3;
    o[0] = s;
    o[1] = e;
    o[2] = val;
}

__device__ __forceinline__ void wave_threshold(
    const int* hist, int K, int ln, int* outB, int* outAbove)
{
    const int h0 = hist[4 * ln + 0], h1 = hist[4 * ln + 1];
    const int h2 = hist[4 * ln + 2], h3 = hist[4 * ln + 3];
    int S = h0 + h1 + h2 + h3;
#pragma unroll
    for (int d = 1; d < 64; d <<= 1) {
        const int t = __shfl_down(S, d, 64);
        if (ln + d < 64) S += t;
    }
    int Snext = __shfl_down(S, 1, 64);
    if (ln == 63) Snext = 0;
    if (S >= K && Snext < K) {
        int acc = Snext, B = 4 * ln, ab = Snext;
        if (acc + h3 >= K)                      { B = 4 * ln + 3; ab = acc; }
        else if (acc + h3 + h2 >= K)            { B = 4 * ln + 2; ab = acc + h3; }
        else if (acc + h3 + h2 + h1 >= K)       { B = 4 * ln + 1; ab = acc + h3 + h2; }
        else                                    { B = 4 * ln + 0; ab = acc + h3 + h2 + h1; }
        *outB = B; *outAbove = ab;
    }
}

__global__ __launch_bounds__(1024) void topk_kernel(
    const float* __restrict__ center, const float* __restrict__ window_,
    const float* __restrict__ offset, float* __restrict__ out)
{
    __shared__ __align__(16) float c[NL];
    __shared__ unsigned long long cand[CAND_CAP];
    __shared__ int hist[256];
    __shared__ int cnt, scnt, sB, sAbove, sTH;

    const int b   = blockIdx.x;
    const int tid = (int)threadIdx.x;
    const int wv  = tid >> 6;
    const int ln  = tid & 63;

    if (tid == 0) { cnt = 0; scnt = 0; }

    {
        const float4* src = (const float4*)(center + b * NL);
        float4* dst = (float4*)c;
#pragma unroll
        for (int k = 0; k < NL / 4096; ++k)
            dst[tid + k * 1024] = src[tid + k * 1024];
    }
    __syncthreads();

#pragma unroll
    for (int k = 0; k < NL / 1024; ++k) {
        const int i = tid + k * 1024;
        const float v = c[i];
        float lm = v;
        if (i >= 2)      lm = fmaxf(lm, c[i - 2]);
        if (i >= 1)      lm = fmaxf(lm, c[i - 1]);
        if (i + 1 < NL)  lm = fmaxf(lm, c[i + 1]);
        if (i + 2 < NL)  lm = fmaxf(lm, c[i + 2]);
        const bool keep = (v > 0.f) && (v == lm);
        const unsigned long long mask = __ballot(keep);
        int base = 0;
        if (ln == 0 && mask) base = atomicAdd(&cnt, __popcll(mask));
        base = __shfl(base, 0, 64);
        if (keep) {
            const int pos = base + __popcll(mask & ((1ull << ln) - 1ull));
            if (pos < CAND_CAP) {
                cand[pos] = ((unsigned long long)__float_as_uint(v) << 32) |
                            (unsigned long long)(0xFFFFFFFFu - (unsigned)i);
            }
        }
    }
    __syncthreads();

    const int C = (cnt < CAND_CAP) ? cnt : CAND_CAP;
    bool fullpath = (C <= 2 * NTOPK);

    if (!fullpath) {
        if (tid < 256) hist[tid] = 0;
        __syncthreads();
        for (int i = tid; i < C; i += 1024)
            atomicAdd(&hist[(unsigned)(cand[i] >> 32) >> 22], 1);
        __syncthreads();
        if (wv == 0) wave_threshold(hist, NTOPK, ln, &sB, &sAbove);
        __syncthreads();
        const int B = sB, above = sAbove;

        if (tid < 256) hist[tid] = 0;
        __syncthreads();
        for (int i = tid; i < C; i += 1024) {
            const unsigned u = (unsigned)(cand[i] >> 32);
            if ((int)(u >> 22) == B) atomicAdd(&hist[(u >> 14) & 0xFF], 1);
        }
        __syncthreads();
        if (wv == 0) {
            int F = 0, dummy = 0;
            wave_threshold(hist, NTOPK - above, ln, &F, &dummy);
            int th = (F == 0 && dummy == 0) ? 0 : (F << 14);
#pragma unroll
            for (int d = 1; d < 64; d <<= 1) th |= __shfl_xor(th, d, 64);
            if (ln == 0) sTH = (B << 22) | th;
        }
        __syncthreads();
        const unsigned TH = (unsigned)sTH;

        unsigned long long* subk = (unsigned long long*)c;
        for (int i = tid; i < C; i += 1024) {
            const unsigned long long ki = cand[i];
            const bool sel = ((unsigned)(ki >> 32) >= TH);
            const unsigned long long mask = __ballot(sel);
            int base = 0;
            if (ln == 0 && mask) base = atomicAdd(&scnt, __popcll(mask));
            base = __shfl(base, 0, 64);
            if (sel) {
                const int p = base + __popcll(mask & ((1ull << ln) - 1ull));
                if (p < SUBCAP) subk[p] = ki;
            }
        }
        __syncthreads();

        if (scnt > SUBCAP) {
            fullpath = true;
        } else {
            const int S = scnt;
            for (int i = tid; i < S; i += 1024) {
                const unsigned long long ki = subk[i];
                int r = 0;
                for (int j = 0; j < S; ++j) r += (subk[j] > ki) ? 1 : 0;
                if (r < NTOPK) {
                    const int idx = (int)(0xFFFFFFFFu - (unsigned)(ki & 0xFFFFFFFFull));
                    const float val = __uint_as_float((unsigned)(ki >> 32));
                    emit_one(b, r, idx, val, window_, offset, out);
                }
            }
        }
    }

    if (fullpath) {
        for (int i = tid; i < C; i += 1024) {
            const unsigned long long ki = cand[i];
            int r = 0;
            for (int j = 0; j < C; ++j) r += (cand[j] > ki) ? 1 : 0;
            if (r < NTOPK) {
                const int idx = (int)(0xFFFFFFFFu - (unsigned)(ki & 0xFFFFFFFFull));
                const float val = __uint_as_float((unsigned)(ki >> 32));
                emit_one(b, r, idx, val, window_, offset, out);
            }
        }
        if (C < NTOPK) {
            __syncthreads();
            if (tid == 0) {
                int r = C;
                for (int i = 0; i < NL && r < NTOPK; ++i) {
                    const float v = c[i];
                    bool keep = false;
                    if (v > 0.f) {
                        float lm = v;
                        if (i >= 2)     lm = fmaxf(lm, c[i - 2]);
                        if (i >= 1)     lm = fmaxf(lm, c[i - 1]);
                        if (i + 1 < NL) lm = fmaxf(lm, c[i + 1]);
                        if (i + 2 < NL) lm = fmaxf(lm, c[i + 2]);
                        keep = (v == lm);
                    }
                    if (!keep) {
                        emit_one(b, r, i, 0.f, window_, offset, out);
                        ++r;
                    }
                }
            }
        }
    }
}

// ---------------------------------------------------------------------------
extern "C" void kernel_launch(void* const* d_in, const int* in_sizes, int n_in,
                              void* d_out, int out_size, void* d_ws, size_t ws_size,
                              hipStream_t stream)
{
    const float* x   = (const float*)d_in[0];
    const float* sal = (const float*)d_in[1];
    const float* Wc  = (const float*)d_in[2];
    const float* bc  = (const float*)d_in[3];
    const float* Ww  = (const float*)d_in[4];
    const float* bw  = (const float*)d_in[5];
    const float* Wo  = (const float*)d_in[6];
    const float* bo  = (const float*)d_in[7];
    float* out = (float*)d_out;

    float* ws      = (float*)d_ws;
    float* center  = ws;                 // [NB*NL]
    float* window_ = ws + NB * NL;       // [NB*NL]
    float* offset  = ws + 2 * NB * NL;   // [NB*NL]

    proj_kernel<<<NBLOCKS, 256, 0, stream>>>(x, sal, Wc, bc, Ww, bw, Wo, bo,
                                             center, window_, offset);

    topk_kernel<<<NB, 1024, 0, stream>>>(center, window_, offset, out);
}